// Round 8
// baseline (459.548 us; speedup 1.0000x reference)
//
#include <hip/hip_runtime.h>
#include <hip/hip_bf16.h>

#define NU 8192
#define NI 4096
#define DE 64
#define ELL_U 80
#define ELL_I 112
#define EPSF 1e-7f

#define NBLK 2048
#define NTHR 256
#define TOTTHR (NBLK * NTHR) /* 524288 threads, 8192 waves */
#define NWAVE (TOTTHR / 64)  /* 8192 */
#define NGRP 64
#define GRPSZ (NBLK / NGRP) /* 32 */

typedef unsigned int u32;

__device__ __forceinline__ float b2f(__hip_bfloat16 x) { return __bfloat162float(x); }

// sc1 (agent-scope relaxed) store: write-through to the coherent LLC, no dirty
// L2 line. All cross-phase workspace writes use this; consumers use NORMAL
// cached loads, which is sound because every buffer is SSA (written once,
// before first read, never rewritten) -> a consumer's first touch misses L2
// and fetches the final value from the LLC.
template <typename T>
__device__ __forceinline__ void st_dev(T* p, T v) {
    __hip_atomic_store(p, v, __ATOMIC_RELAXED, __HIP_MEMORY_SCOPE_AGENT);
}

// ---- full-SSA workspace layout (compile-time offsets; ~53 MB of 512 MB) ----
struct WS {
    int bar[8192];                       // barrier counters + release words (32 KB)
    int cnt_u[NU]; int cnt_i[NI]; int flag; int pad[63];
    u32 idx_u[NU * ELL_U]; u32 idx_i[NI * ELL_I];
    float a_f[NI]; float p_f[NU]; float b_f[NU]; float q_f[NI];
    float dv_u[NU]; float de1sq_u[NI]; float de2sq_u[NI];
    float dv_i[NI]; float de1sq_i[NU]; float de2sq_i[NU];
    float Xu[3][NU * DE]; float Xsu[3][NU * DE];   // X generations 0,1,2
    float Xi[3][NI * DE]; float Xsi[3][NI * DE];
    float T1u[2][NI * DE]; float T2u[2][NU * DE]; float T3u[2][NI * DE];
    float T4u[2][NU * DE]; float Su[2][NI * DE];   // per-layer fresh temps (u chan)
    float T1i[2][NU * DE]; float T2i[2][NI * DE]; float T3i[2][NU * DE];
    float T4i[2][NI * DE]; float Si[2][NU * DE];   // per-layer fresh temps (i chan)
};

struct Job {
    const int* cnt; const u32* idx; int ell; int nrows;
    const float* src; float* dst; const float* evec; const float* aux;
    const float* xin; const float* dvv; float* xnext; float* xsout;
    size_t obase; int coloff;
};

// ---- grid barrier v7b: hierarchical arrive + per-group release broadcast ----
// 64 groups of 32 blocks; group counters 128B apart; group-last bumps root
// (<=64 RMWs); global-last broadcasts epoch to 64 release words; each block
// polls its own group's word (32 pollers/line) with s_sleep(16) backoff.
// bar layout (int idx): root=bar[0]; arrive[g]=bar[256+g*32];
//                       release[g]=bar[4096+g*32].
__device__ __forceinline__ void gbar(int* bar, int& ep) {
    __syncthreads();  // drains vmcnt: all sc1 stores acked at LLC
    ep += 1;
    if (threadIdx.x == 0) {
        int g = blockIdx.x >> 5;  // 64 groups of 32 blocks
        int prev = __hip_atomic_fetch_add(&bar[256 + g * 32], 1, __ATOMIC_RELAXED,
                                          __HIP_MEMORY_SCOPE_AGENT);
        if (prev == ep * GRPSZ - 1) {  // last arriver of this group this epoch
            int pr = __hip_atomic_fetch_add(&bar[0], 1, __ATOMIC_RELAXED,
                                            __HIP_MEMORY_SCOPE_AGENT);
            if (pr == ep * NGRP - 1) {  // global last: broadcast release
#pragma unroll
                for (int g2 = 0; g2 < NGRP; ++g2)
                    __hip_atomic_store(&bar[4096 + g2 * 32], ep, __ATOMIC_RELAXED,
                                       __HIP_MEMORY_SCOPE_AGENT);
            }
        }
        while (__hip_atomic_load(&bar[4096 + g * 32], __ATOMIC_RELAXED,
                                 __HIP_MEMORY_SCOPE_AGENT) < ep)
            __builtin_amdgcn_s_sleep(16);
    }
    asm volatile("" ::: "memory");  // no load hoisting above the spin
    __syncthreads();
}

// scalar per-thread SpMV row (int or float source); normal cached loads
__device__ __forceinline__ float spmv_row(int n, const u32* __restrict__ ip,
                                          const void* __restrict__ s, int isint) {
    float a0 = 0.f, a1 = 0.f, a2 = 0.f, a3 = 0.f;
    int p = 0;
    if (isint) {
        const int* sv = (const int*)s;
        for (; p + 4 <= n; p += 4) {
            uint4 cc = *(const uint4*)(ip + p);
            a0 += (float)sv[cc.x]; a1 += (float)sv[cc.y];
            a2 += (float)sv[cc.z]; a3 += (float)sv[cc.w];
        }
        for (; p < n; p++) a0 += (float)sv[ip[p]];
    } else {
        const float* sv = (const float*)s;
        for (; p + 4 <= n; p += 4) {
            uint4 cc = *(const uint4*)(ip + p);
            a0 += sv[cc.x]; a1 += sv[cc.y]; a2 += sv[cc.z]; a3 += sv[cc.w];
        }
        for (; p < n; p++) a0 += sv[ip[p]];
    }
    return (a0 + a1) + (a2 + a3);
}

// one wave gathers/accumulates one 64-col row; 8 loads in flight; cached loads
__device__ __forceinline__ float gather_row(int n, const u32* __restrict__ ip,
                                            const float* __restrict__ src, int lane) {
    float a0 = 0.f, a1 = 0.f, a2 = 0.f, a3 = 0.f;
    float a4 = 0.f, a5 = 0.f, a6 = 0.f, a7 = 0.f;
    int p = 0;
    if (n >= 8) {
        uint4 cA = *(const uint4*)(ip);
        uint4 cB = *(const uint4*)(ip + 4);
        while (p + 8 <= n) {
            float g0 = src[((size_t)cA.x << 6) + lane];
            float g1 = src[((size_t)cA.y << 6) + lane];
            float g2 = src[((size_t)cA.z << 6) + lane];
            float g3 = src[((size_t)cA.w << 6) + lane];
            float g4 = src[((size_t)cB.x << 6) + lane];
            float g5 = src[((size_t)cB.y << 6) + lane];
            float g6 = src[((size_t)cB.z << 6) + lane];
            float g7 = src[((size_t)cB.w << 6) + lane];
            p += 8;
            // prefetch next batch's indices (overreads <=32B into padding/next row)
            cA = *(const uint4*)(ip + p);
            cB = *(const uint4*)(ip + p + 4);
            a0 += g0; a1 += g1; a2 += g2; a3 += g3;
            a4 += g4; a5 += g5; a6 += g6; a7 += g7;
        }
    }
    if (p + 4 <= n) {
        uint4 cc = *(const uint4*)(ip + p);
        a0 += src[((size_t)cc.x << 6) + lane];
        a1 += src[((size_t)cc.y << 6) + lane];
        a2 += src[((size_t)cc.z << 6) + lane];
        a3 += src[((size_t)cc.w << 6) + lane];
        p += 4;
    }
    for (; p < n; p++) a4 += src[((size_t)ip[p] << 6) + lane];
    return ((a0 + a1) + (a2 + a3)) + ((a4 + a5) + (a6 + a7));
}

// process one output row of one job
__device__ __forceinline__ void do_row(const Job& J, int row, int mode,
                                       const void* w, const void* bias, void* outp,
                                       int isbf, int lane) {
    int n = min(J.cnt[row], J.ell);
    const u32* ip = J.idx + (size_t)row * J.ell;
    float acc = gather_row(n, ip, J.src, lane);
    size_t o = ((size_t)row << 6) + lane;
    if (mode == 0) {
        st_dev(J.dst + o, acc);
    } else if (mode == 1) {
        st_dev(J.dst + o, J.evec[row] * acc);
    } else if (mode == 2) {
        st_dev(J.dst + o, acc + J.evec[row] * J.aux[o]);
    } else {
        // M = dv*acc + X ; Xnext = M @ w + b ; emit output in detected dtype
        float dvr = J.dvv[row];
        float m = dvr * acc + J.xin[o];
        float x0, x1 = 0.f, x2 = 0.f, x3 = 0.f;
        if (isbf) {
            const __hip_bfloat16* __restrict__ wp = (const __hip_bfloat16*)w;
            x0 = b2f(((const __hip_bfloat16*)bias)[lane]);
            for (int k = 0; k < 64; k += 4) {
                x0 = fmaf(__shfl(m, k, 64), b2f(wp[(k << 6) + lane]), x0);
                x1 = fmaf(__shfl(m, k + 1, 64), b2f(wp[((k + 1) << 6) + lane]), x1);
                x2 = fmaf(__shfl(m, k + 2, 64), b2f(wp[((k + 2) << 6) + lane]), x2);
                x3 = fmaf(__shfl(m, k + 3, 64), b2f(wp[((k + 3) << 6) + lane]), x3);
            }
        } else {
            const float* __restrict__ wp = (const float*)w;
            x0 = ((const float*)bias)[lane];
            for (int k = 0; k < 64; k += 4) {
                x0 = fmaf(__shfl(m, k, 64), wp[(k << 6) + lane], x0);
                x1 = fmaf(__shfl(m, k + 1, 64), wp[((k + 1) << 6) + lane], x1);
                x2 = fmaf(__shfl(m, k + 2, 64), wp[((k + 2) << 6) + lane], x2);
                x3 = fmaf(__shfl(m, k + 3, 64), wp[((k + 3) << 6) + lane], x3);
            }
        }
        float xn = (x0 + x1) + (x2 + x3);
        st_dev(J.xnext + o, xn);
        st_dev(J.xsout + o, dvr * xn);  // dv-premultiplied for next layer's s1
        size_t oo = J.obase + (size_t)row * 192 + J.coloff + lane;
        if (isbf) ((__hip_bfloat16*)outp)[oo] = __float2bfloat16(xn);
        else ((float*)outp)[oo] = xn;
    }
}

// one SpMM phase over both channels. Balanced static mapping for 8192 waves:
// every phase has one HEAVY job (NI=4096 rows, ~41 nnz avg via idx_i) and one
// LIGHT job (NU=8192 rows, ~20 nnz avg via idx_u). Waves 0..4095 take one
// heavy row; waves 4096..8191 take two light rows -> ~41 nnz per wave uniform.
__device__ __forceinline__ void spmm_phase(const Job& j0, const Job& j1, int mode,
                                           const void* w, const void* bias, void* outp,
                                           int isbf, int gwave, int lane) {
    const Job& Hv = (j0.nrows == NI) ? j0 : j1;
    const Job& Lt = (j0.nrows == NI) ? j1 : j0;
    if (gwave < NI) {
        do_row(Hv, gwave, mode, w, bias, outp, isbf, lane);
    } else {
        int r = (gwave - NI) * 2;
        do_row(Lt, r, mode, w, bias, outp, isbf, lane);
        do_row(Lt, r + 1, mode, w, bias, outp, isbf, lane);
    }
}

__device__ __forceinline__ Job mkjob(const int* cnt, const u32* idx, int ell, int nrows,
                                     const float* src, float* dst, const float* evec,
                                     const float* aux, const float* xin, const float* dvv,
                                     float* xnext, float* xsout, size_t obase, int coloff) {
    Job J;
    J.cnt = cnt; J.idx = idx; J.ell = ell; J.nrows = nrows;
    J.src = src; J.dst = dst; J.evec = evec; J.aux = aux;
    J.xin = xin; J.dvv = dvv; J.xnext = xnext; J.xsout = xsout;
    J.obase = obase; J.coloff = coloff;
    return J;
}

// ---------------- init: zero counters / flag / barrier ----------------

__global__ __launch_bounds__(256) void init_k(WS* W) {
    int t = blockIdx.x * 256 + threadIdx.x;
    if (t == 0) W->flag = 0;
    if (t < 8192) W->bar[t] = 0;
    if (t < NU) W->cnt_u[t] = 0;
    int s = t - NU;
    if (s >= 0 && s < NI) W->cnt_i[s] = 0;
}

// dtype probe: H values are exactly 0.0/1.0. fp32 words are 0x00000000/0x3F800000
// (low u16 always 0). bf16 pairs expose 0x3F80 in the low u16 for even-col nnz.
__global__ __launch_bounds__(256) void detect_dtype(const u32* __restrict__ Hw, WS* W) {
    int t = blockIdx.x * 256 + threadIdx.x;  // 131072 threads
    u32 w = Hw[t];
    if ((w & 0xFFFFu) == 0x3F80u) W->flag = 1;  // benign same-value race
}

// ---------------- the single fused kernel (self-barriered, SSA) ----------------

struct FArgs {
    const void* Hp; const void* ue; const void* ie;
    const void* w0; const void* b0; const void* w1; const void* b1;
    WS* W; void* outp;
};

__global__ __launch_bounds__(NTHR, 8) void fused(FArgs A) {
    WS* W = A.W;
    const int tid = blockIdx.x * NTHR + threadIdx.x;
    const int lane = threadIdx.x & 63;
    const int gwave = tid >> 6;
    int ep = 0;
    const int isbf = W->flag;  // written by detect_dtype (prior dispatch)

    // ---- P2: fill ELL lists for H and H^T (grid-stride, 8 elems/thread/iter) ----
    // cnt via agent atomicAdd (LLC); idx via sc1 stores.
    for (int t = tid; t < NU * NI / 8; t += TOTTHR) {
        int flat = t << 3;
        int i = flat >> 12;    // user row
        int j0 = flat & 4095;  // col base
        u32 words[8];
        if (isbf) {
            uint4 v = ((const uint4*)A.Hp)[t];
            u32 p4[4] = {v.x, v.y, v.z, v.w};
#pragma unroll
            for (int q = 0; q < 4; q++) {
                words[2 * q] = p4[q] & 0xFFFFu;
                words[2 * q + 1] = p4[q] >> 16;
            }
        } else {
            uint4 a = ((const uint4*)A.Hp)[2 * t];
            uint4 b = ((const uint4*)A.Hp)[2 * t + 1];
            words[0] = a.x; words[1] = a.y; words[2] = a.z; words[3] = a.w;
            words[4] = b.x; words[5] = b.y; words[6] = b.z; words[7] = b.w;
        }
#pragma unroll
        for (int e = 0; e < 8; e++) {
            if (words[e]) {
                int j = j0 + e;
                int pu = atomicAdd(&W->cnt_u[i], 1);
                if (pu < ELL_U) st_dev(&W->idx_u[i * ELL_U + pu], (u32)j);
                int pi = atomicAdd(&W->cnt_i[j], 1);
                if (pi < ELL_I) st_dev(&W->idx_i[j * ELL_I + pi], (u32)i);
            }
        }
    }
    gbar(W->bar, ep);

    // ---- P3: a = H^T r (item rows, int src), p = H c (user rows, int src) ----
    if (tid < NI) {
        int n = min(W->cnt_i[tid], ELL_I);
        st_dev(&W->a_f[tid], spmv_row(n, W->idx_i + (size_t)tid * ELL_I, W->cnt_u, 1));
    } else {
        int r = tid - NI;
        if (r < NU) {
            int n = min(W->cnt_u[r], ELL_U);
            st_dev(&W->p_f[r], spmv_row(n, W->idx_u + (size_t)r * ELL_U, W->cnt_i, 1));
        }
    }
    gbar(W->bar, ep);

    // ---- P4: b = H a (user rows), q = H^T p (item rows) ----
    if (tid < NU) {
        int n = min(W->cnt_u[tid], ELL_U);
        st_dev(&W->b_f[tid], spmv_row(n, W->idx_u + (size_t)tid * ELL_U, W->a_f, 0));
    } else {
        int r = tid - NU;
        if (r < NI) {
            int n = min(W->cnt_i[r], ELL_I);
            st_dev(&W->q_f[r], spmv_row(n, W->idx_i + (size_t)r * ELL_I, W->p_f, 0));
        }
    }
    gbar(W->bar, ep);

    // ---- P5: degree vectors + fp32 working copies + layer-0 output cols ----
    if (tid < NU) {
        float r = (float)W->cnt_u[tid];
        float bf_ = W->b_f[tid];
        st_dev(&W->dv_u[tid], 1.0f / sqrtf(r + bf_ + EPSF));
        st_dev(&W->de1sq_i[tid], 1.0f / (r + EPSF));
        st_dev(&W->de2sq_i[tid], 1.0f / (bf_ + EPSF));
    }
    if (tid < NI) {
        float cdeg = (float)W->cnt_i[tid];
        float qf_ = W->q_f[tid];
        st_dev(&W->dv_i[tid], 1.0f / sqrtf(cdeg + qf_ + EPSF));
        st_dev(&W->de1sq_u[tid], 1.0f / (cdeg + EPSF));
        st_dev(&W->de2sq_u[tid], 1.0f / (qf_ + EPSF));
    }
    for (int t = tid; t < (NU + NI) * DE; t += TOTTHR) {
        if (t < NU * DE) {
            int i = t >> 6, l = t & 63;
            float v = isbf ? b2f(((const __hip_bfloat16*)A.ue)[t]) : ((const float*)A.ue)[t];
            st_dev(&W->Xu[0][t], v);
            float dv = 1.0f / sqrtf((float)W->cnt_u[i] + W->b_f[i] + EPSF);
            st_dev(&W->Xsu[0][t], dv * v);
            size_t o = (size_t)i * 192 + l;
            if (isbf) ((__hip_bfloat16*)A.outp)[o] = __float2bfloat16(v);
            else ((float*)A.outp)[o] = v;
        } else {
            int s = t - NU * DE;
            int i = s >> 6, l = s & 63;
            float v = isbf ? b2f(((const __hip_bfloat16*)A.ie)[s]) : ((const float*)A.ie)[s];
            st_dev(&W->Xi[0][s], v);
            float dv = 1.0f / sqrtf((float)W->cnt_i[i] + W->q_f[i] + EPSF);
            st_dev(&W->Xsi[0][s], dv * v);
            size_t o = (size_t)(NU + i) * 192 + l;
            if (isbf) ((__hip_bfloat16*)A.outp)[o] = __float2bfloat16(v);
            else ((float*)A.outp)[o] = v;
        }
    }
    gbar(W->bar, ep);

    // ---- P6..: the 12 SpMM phases (6 per layer, both channels; all SSA) ----
    for (int layer = 0; layer < 2; ++layer) {
        const void* w = layer ? A.w1 : A.w0;
        const void* bb = layer ? A.b1 : A.b0;
        int coloff = 64 + 64 * layer;

        // s1: T1 = A^T Xs
        spmm_phase(mkjob(W->cnt_i, W->idx_i, ELL_I, NI, W->Xsu[layer], W->T1u[layer],
                         0, 0, 0, 0, 0, 0, 0, 0),
                   mkjob(W->cnt_u, W->idx_u, ELL_U, NU, W->Xsi[layer], W->T1i[layer],
                         0, 0, 0, 0, 0, 0, 0, 0),
                   0, w, bb, A.outp, isbf, gwave, lane);
        gbar(W->bar, ep);
        // s2: T2 = A T1
        spmm_phase(mkjob(W->cnt_u, W->idx_u, ELL_U, NU, W->T1u[layer], W->T2u[layer],
                         0, 0, 0, 0, 0, 0, 0, 0),
                   mkjob(W->cnt_i, W->idx_i, ELL_I, NI, W->T1i[layer], W->T2i[layer],
                         0, 0, 0, 0, 0, 0, 0, 0),
                   0, w, bb, A.outp, isbf, gwave, lane);
        gbar(W->bar, ep);
        // s3: T3 = de2sq o (A^T T2)
        spmm_phase(mkjob(W->cnt_i, W->idx_i, ELL_I, NI, W->T2u[layer], W->T3u[layer],
                         W->de2sq_u, 0, 0, 0, 0, 0, 0, 0),
                   mkjob(W->cnt_u, W->idx_u, ELL_U, NU, W->T2i[layer], W->T3i[layer],
                         W->de2sq_i, 0, 0, 0, 0, 0, 0, 0),
                   1, w, bb, A.outp, isbf, gwave, lane);
        gbar(W->bar, ep);
        // s4: T4 = A T3
        spmm_phase(mkjob(W->cnt_u, W->idx_u, ELL_U, NU, W->T3u[layer], W->T4u[layer],
                         0, 0, 0, 0, 0, 0, 0, 0),
                   mkjob(W->cnt_i, W->idx_i, ELL_I, NI, W->T3i[layer], W->T4i[layer],
                         0, 0, 0, 0, 0, 0, 0, 0),
                   0, w, bb, A.outp, isbf, gwave, lane);
        gbar(W->bar, ep);
        // s5: S = A^T T4 + de1sq o T1
        spmm_phase(mkjob(W->cnt_i, W->idx_i, ELL_I, NI, W->T4u[layer], W->Su[layer],
                         W->de1sq_u, W->T1u[layer], 0, 0, 0, 0, 0, 0),
                   mkjob(W->cnt_u, W->idx_u, ELL_U, NU, W->T4i[layer], W->Si[layer],
                         W->de1sq_i, W->T1i[layer], 0, 0, 0, 0, 0, 0),
                   2, w, bb, A.outp, isbf, gwave, lane);
        gbar(W->bar, ep);
        // s6: M = dv o (A S) + X ; Xnext = M w + b ; Xs' = dv o Xnext ; emit out
        spmm_phase(mkjob(W->cnt_u, W->idx_u, ELL_U, NU, W->Su[layer], 0, 0, 0,
                         W->Xu[layer], W->dv_u, W->Xu[layer + 1], W->Xsu[layer + 1],
                         0, coloff),
                   mkjob(W->cnt_i, W->idx_i, ELL_I, NI, W->Si[layer], 0, 0, 0,
                         W->Xi[layer], W->dv_i, W->Xi[layer + 1], W->Xsi[layer + 1],
                         (size_t)NU * 192, coloff),
                   3, w, bb, A.outp, isbf, gwave, lane);
        if (layer == 0) gbar(W->bar, ep);  // Xu[1]/Xsu[1] feed next layer
    }
}

// ---------------- host ----------------

extern "C" void kernel_launch(void* const* d_in, const int* in_sizes, int n_in,
                              void* d_out, int out_size, void* d_ws, size_t ws_size,
                              hipStream_t stream) {
    FArgs A;
    A.Hp = d_in[0];
    A.ue = d_in[1];
    A.ie = d_in[2];
    A.w0 = d_in[3];
    A.b0 = d_in[4];
    A.w1 = d_in[5];
    A.b1 = d_in[6];
    A.W = (WS*)d_ws;
    A.outp = d_out;
    (void)ws_size; (void)n_in; (void)in_sizes; (void)out_size;

    init_k<<<(NU + NI) / 256, 256, 0, stream>>>(A.W);
    detect_dtype<<<131072 / 256, 256, 0, stream>>>((const u32*)A.Hp, A.W);
    fused<<<NBLK, NTHR, 0, stream>>>(A);
}

// Round 9
// 427.600 us; speedup vs baseline: 1.0747x; 1.0747x over previous
//
#include <hip/hip_runtime.h>
#include <hip/hip_bf16.h>

#define NU 8192
#define NI 4096
#define DE 64
#define ELL_U 80
#define ELL_I 112
#define EPSF 1e-7f

#define NBLK 2048
#define NTHR 256
#define TOTTHR (NBLK * NTHR) /* 524288 threads, 8192 waves */
#define NWAVE (TOTTHR / 64)  /* 8192 */
#define NGRP 64
#define GRPSZ (NBLK / NGRP) /* 32 */

typedef unsigned int u32;
typedef unsigned short u16;

__device__ __forceinline__ float b2f(__hip_bfloat16 x) { return __bfloat162float(x); }
// raw-bits bf16 <-> fp32 (bf16 = high 16 bits of fp32)
__device__ __forceinline__ float bf2f(u16 v) { return __uint_as_float(((u32)v) << 16); }
__device__ __forceinline__ u16 f2bf(float f) {
    __hip_bfloat16 h = __float2bfloat16(f);  // RNE
    return *(u16*)&h;
}

// sc1 (agent-scope relaxed) store: write-through to the coherent LLC, no dirty
// L2 line. All cross-phase workspace writes use this; consumers use NORMAL
// cached loads, which is sound because every buffer is SSA (written once,
// before first read, never rewritten) -> a consumer's first touch misses L2
// and fetches the final value from the LLC.
template <typename T>
__device__ __forceinline__ void st_dev(T* p, T v) {
    __hip_atomic_store(p, v, __ATOMIC_RELAXED, __HIP_MEMORY_SCOPE_AGENT);
}

// ---- full-SSA workspace layout. GATHERED buffers (Xs, T1..T4, S) are bf16
// rows (64 x 2B = 128B = 2 cache lines/row): r8 showed the gather path is
// saturated on line-request count (occupancy 47->93% = no change), so halving
// bytes/row halves requests. Residual X stays fp32 (elementwise only, carries
// the output magnitude); accumulation stays fp32. ----
struct WS {
    int bar[8192];                       // barrier counters + release words (32 KB)
    int cnt_u[NU]; int cnt_i[NI]; int flag; int pad[63];
    u32 idx_u[NU * ELL_U]; u32 idx_i[NI * ELL_I];
    float a_f[NI]; float p_f[NU]; float b_f[NU]; float q_f[NI];
    float dv_u[NU]; float de1sq_u[NI]; float de2sq_u[NI];
    float dv_i[NI]; float de1sq_i[NU]; float de2sq_i[NU];
    float Xu[3][NU * DE]; float Xi[3][NI * DE];    // residual X, fp32, gens 0..2
    u16 Xsu[3][NU * DE]; u16 Xsi[3][NI * DE];      // dv-premult X, bf16 (gathered)
    u16 T1u[2][NI * DE]; u16 T2u[2][NU * DE]; u16 T3u[2][NI * DE];
    u16 T4u[2][NU * DE]; u16 Su[2][NI * DE];       // per-layer temps, bf16 (u chan)
    u16 T1i[2][NU * DE]; u16 T2i[2][NI * DE]; u16 T3i[2][NU * DE];
    u16 T4i[2][NI * DE]; u16 Si[2][NU * DE];       // per-layer temps, bf16 (i chan)
};

struct Job {
    const int* cnt; const u32* idx; int ell; int nrows;
    const u16* src; u16* dst; const float* evec; const u16* aux;
    const float* xin; const float* dvv; float* xnext; u16* xsout;
    size_t obase; int coloff;
};

// ---- grid barrier v7b: hierarchical arrive + per-group release broadcast ----
// bar layout (int idx): root=bar[0]; arrive[g]=bar[256+g*32];
//                       release[g]=bar[4096+g*32].
__device__ __forceinline__ void gbar(int* bar, int& ep) {
    __syncthreads();  // drains vmcnt: all sc1 stores acked at LLC
    ep += 1;
    if (threadIdx.x == 0) {
        int g = blockIdx.x >> 5;  // 64 groups of 32 blocks
        int prev = __hip_atomic_fetch_add(&bar[256 + g * 32], 1, __ATOMIC_RELAXED,
                                          __HIP_MEMORY_SCOPE_AGENT);
        if (prev == ep * GRPSZ - 1) {  // last arriver of this group this epoch
            int pr = __hip_atomic_fetch_add(&bar[0], 1, __ATOMIC_RELAXED,
                                            __HIP_MEMORY_SCOPE_AGENT);
            if (pr == ep * NGRP - 1) {  // global last: broadcast release
#pragma unroll
                for (int g2 = 0; g2 < NGRP; ++g2)
                    __hip_atomic_store(&bar[4096 + g2 * 32], ep, __ATOMIC_RELAXED,
                                       __HIP_MEMORY_SCOPE_AGENT);
            }
        }
        while (__hip_atomic_load(&bar[4096 + g * 32], __ATOMIC_RELAXED,
                                 __HIP_MEMORY_SCOPE_AGENT) < ep)
            __builtin_amdgcn_s_sleep(16);
    }
    asm volatile("" ::: "memory");  // no load hoisting above the spin
    __syncthreads();
}

// scalar per-thread SpMV row (int or float source); normal cached loads
__device__ __forceinline__ float spmv_row(int n, const u32* __restrict__ ip,
                                          const void* __restrict__ s, int isint) {
    float a0 = 0.f, a1 = 0.f, a2 = 0.f, a3 = 0.f;
    int p = 0;
    if (isint) {
        const int* sv = (const int*)s;
        for (; p + 4 <= n; p += 4) {
            uint4 cc = *(const uint4*)(ip + p);
            a0 += (float)sv[cc.x]; a1 += (float)sv[cc.y];
            a2 += (float)sv[cc.z]; a3 += (float)sv[cc.w];
        }
        for (; p < n; p++) a0 += (float)sv[ip[p]];
    } else {
        const float* sv = (const float*)s;
        for (; p + 4 <= n; p += 4) {
            uint4 cc = *(const uint4*)(ip + p);
            a0 += sv[cc.x]; a1 += sv[cc.y]; a2 += sv[cc.z]; a3 += sv[cc.w];
        }
        for (; p < n; p++) a0 += sv[ip[p]];
    }
    return (a0 + a1) + (a2 + a3);
}

// one wave gathers/accumulates one 64-col bf16 row; 8 loads in flight
__device__ __forceinline__ float gather_row(int n, const u32* __restrict__ ip,
                                            const u16* __restrict__ src, int lane) {
    float a0 = 0.f, a1 = 0.f, a2 = 0.f, a3 = 0.f;
    float a4 = 0.f, a5 = 0.f, a6 = 0.f, a7 = 0.f;
    int p = 0;
    if (n >= 8) {
        uint4 cA = *(const uint4*)(ip);
        uint4 cB = *(const uint4*)(ip + 4);
        while (p + 8 <= n) {
            u16 g0 = src[((size_t)cA.x << 6) + lane];
            u16 g1 = src[((size_t)cA.y << 6) + lane];
            u16 g2 = src[((size_t)cA.z << 6) + lane];
            u16 g3 = src[((size_t)cA.w << 6) + lane];
            u16 g4 = src[((size_t)cB.x << 6) + lane];
            u16 g5 = src[((size_t)cB.y << 6) + lane];
            u16 g6 = src[((size_t)cB.z << 6) + lane];
            u16 g7 = src[((size_t)cB.w << 6) + lane];
            p += 8;
            // prefetch next batch's indices (overreads <=32B into padding/next row)
            cA = *(const uint4*)(ip + p);
            cB = *(const uint4*)(ip + p + 4);
            a0 += bf2f(g0); a1 += bf2f(g1); a2 += bf2f(g2); a3 += bf2f(g3);
            a4 += bf2f(g4); a5 += bf2f(g5); a6 += bf2f(g6); a7 += bf2f(g7);
        }
    }
    if (p + 4 <= n) {
        uint4 cc = *(const uint4*)(ip + p);
        a0 += bf2f(src[((size_t)cc.x << 6) + lane]);
        a1 += bf2f(src[((size_t)cc.y << 6) + lane]);
        a2 += bf2f(src[((size_t)cc.z << 6) + lane]);
        a3 += bf2f(src[((size_t)cc.w << 6) + lane]);
        p += 4;
    }
    for (; p < n; p++) a4 += bf2f(src[((size_t)ip[p] << 6) + lane]);
    return ((a0 + a1) + (a2 + a3)) + ((a4 + a5) + (a6 + a7));
}

// process one output row of one job
__device__ __forceinline__ void do_row(const Job& J, int row, int mode,
                                       const void* w, const void* bias, void* outp,
                                       int isbf, int lane) {
    int n = min(J.cnt[row], J.ell);
    const u32* ip = J.idx + (size_t)row * J.ell;
    float acc = gather_row(n, ip, J.src, lane);
    size_t o = ((size_t)row << 6) + lane;
    if (mode == 0) {
        st_dev(J.dst + o, f2bf(acc));
    } else if (mode == 1) {
        st_dev(J.dst + o, f2bf(J.evec[row] * acc));
    } else if (mode == 2) {
        st_dev(J.dst + o, f2bf(acc + J.evec[row] * bf2f(J.aux[o])));
    } else {
        // M = dv*acc + X ; Xnext = M @ w + b ; emit output in detected dtype
        float dvr = J.dvv[row];
        float m = dvr * acc + J.xin[o];
        float x0, x1 = 0.f, x2 = 0.f, x3 = 0.f;
        if (isbf) {
            const __hip_bfloat16* __restrict__ wp = (const __hip_bfloat16*)w;
            x0 = b2f(((const __hip_bfloat16*)bias)[lane]);
            for (int k = 0; k < 64; k += 4) {
                x0 = fmaf(__shfl(m, k, 64), b2f(wp[(k << 6) + lane]), x0);
                x1 = fmaf(__shfl(m, k + 1, 64), b2f(wp[((k + 1) << 6) + lane]), x1);
                x2 = fmaf(__shfl(m, k + 2, 64), b2f(wp[((k + 2) << 6) + lane]), x2);
                x3 = fmaf(__shfl(m, k + 3, 64), b2f(wp[((k + 3) << 6) + lane]), x3);
            }
        } else {
            const float* __restrict__ wp = (const float*)w;
            x0 = ((const float*)bias)[lane];
            for (int k = 0; k < 64; k += 4) {
                x0 = fmaf(__shfl(m, k, 64), wp[(k << 6) + lane], x0);
                x1 = fmaf(__shfl(m, k + 1, 64), wp[((k + 1) << 6) + lane], x1);
                x2 = fmaf(__shfl(m, k + 2, 64), wp[((k + 2) << 6) + lane], x2);
                x3 = fmaf(__shfl(m, k + 3, 64), wp[((k + 3) << 6) + lane], x3);
            }
        }
        float xn = (x0 + x1) + (x2 + x3);
        st_dev(J.xnext + o, xn);                 // residual X stays fp32
        st_dev(J.xsout + o, f2bf(dvr * xn));     // dv-premult for next s1, bf16
        size_t oo = J.obase + (size_t)row * 192 + J.coloff + lane;
        if (isbf) ((__hip_bfloat16*)outp)[oo] = __float2bfloat16(xn);
        else ((float*)outp)[oo] = xn;
    }
}

// one SpMM phase over both channels. Balanced static mapping for 8192 waves:
// every phase has one HEAVY job (NI=4096 rows, ~41 nnz avg via idx_i) and one
// LIGHT job (NU=8192 rows, ~20 nnz avg via idx_u). Waves 0..4095 take one
// heavy row; waves 4096..8191 take two light rows -> ~41 nnz per wave uniform.
__device__ __forceinline__ void spmm_phase(const Job& j0, const Job& j1, int mode,
                                           const void* w, const void* bias, void* outp,
                                           int isbf, int gwave, int lane) {
    const Job& Hv = (j0.nrows == NI) ? j0 : j1;
    const Job& Lt = (j0.nrows == NI) ? j1 : j0;
    if (gwave < NI) {
        do_row(Hv, gwave, mode, w, bias, outp, isbf, lane);
    } else {
        int r = (gwave - NI) * 2;
        do_row(Lt, r, mode, w, bias, outp, isbf, lane);
        do_row(Lt, r + 1, mode, w, bias, outp, isbf, lane);
    }
}

__device__ __forceinline__ Job mkjob(const int* cnt, const u32* idx, int ell, int nrows,
                                     const u16* src, u16* dst, const float* evec,
                                     const u16* aux, const float* xin, const float* dvv,
                                     float* xnext, u16* xsout, size_t obase, int coloff) {
    Job J;
    J.cnt = cnt; J.idx = idx; J.ell = ell; J.nrows = nrows;
    J.src = src; J.dst = dst; J.evec = evec; J.aux = aux;
    J.xin = xin; J.dvv = dvv; J.xnext = xnext; J.xsout = xsout;
    J.obase = obase; J.coloff = coloff;
    return J;
}

// ---------------- init: zero counters / flag / barrier ----------------

__global__ __launch_bounds__(256) void init_k(WS* W) {
    int t = blockIdx.x * 256 + threadIdx.x;
    if (t == 0) W->flag = 0;
    if (t < 8192) W->bar[t] = 0;
    if (t < NU) W->cnt_u[t] = 0;
    int s = t - NU;
    if (s >= 0 && s < NI) W->cnt_i[s] = 0;
}

// dtype probe: H values are exactly 0.0/1.0. fp32 words are 0x00000000/0x3F800000
// (low u16 always 0). bf16 pairs expose 0x3F80 in the low u16 for even-col nnz.
__global__ __launch_bounds__(256) void detect_dtype(const u32* __restrict__ Hw, WS* W) {
    int t = blockIdx.x * 256 + threadIdx.x;  // 131072 threads
    u32 w = Hw[t];
    if ((w & 0xFFFFu) == 0x3F80u) W->flag = 1;  // benign same-value race
}

// ---------------- the single fused kernel (self-barriered, SSA) ----------------

struct FArgs {
    const void* Hp; const void* ue; const void* ie;
    const void* w0; const void* b0; const void* w1; const void* b1;
    WS* W; void* outp;
};

__global__ __launch_bounds__(NTHR, 8) void fused(FArgs A) {
    WS* W = A.W;
    const int tid = blockIdx.x * NTHR + threadIdx.x;
    const int lane = threadIdx.x & 63;
    const int gwave = tid >> 6;
    int ep = 0;
    const int isbf = W->flag;  // written by detect_dtype (prior dispatch)

    // ---- P2: fill ELL lists for H and H^T (grid-stride, 8 elems/thread/iter) ----
    // cnt via agent atomicAdd (LLC); idx via sc1 stores.
    for (int t = tid; t < NU * NI / 8; t += TOTTHR) {
        int flat = t << 3;
        int i = flat >> 12;    // user row
        int j0 = flat & 4095;  // col base
        u32 words[8];
        if (isbf) {
            uint4 v = ((const uint4*)A.Hp)[t];
            u32 p4[4] = {v.x, v.y, v.z, v.w};
#pragma unroll
            for (int q = 0; q < 4; q++) {
                words[2 * q] = p4[q] & 0xFFFFu;
                words[2 * q + 1] = p4[q] >> 16;
            }
        } else {
            uint4 a = ((const uint4*)A.Hp)[2 * t];
            uint4 b = ((const uint4*)A.Hp)[2 * t + 1];
            words[0] = a.x; words[1] = a.y; words[2] = a.z; words[3] = a.w;
            words[4] = b.x; words[5] = b.y; words[6] = b.z; words[7] = b.w;
        }
#pragma unroll
        for (int e = 0; e < 8; e++) {
            if (words[e]) {
                int j = j0 + e;
                int pu = atomicAdd(&W->cnt_u[i], 1);
                if (pu < ELL_U) st_dev(&W->idx_u[i * ELL_U + pu], (u32)j);
                int pi = atomicAdd(&W->cnt_i[j], 1);
                if (pi < ELL_I) st_dev(&W->idx_i[j * ELL_I + pi], (u32)i);
            }
        }
    }
    gbar(W->bar, ep);

    // ---- P3: a = H^T r (item rows, int src), p = H c (user rows, int src) ----
    if (tid < NI) {
        int n = min(W->cnt_i[tid], ELL_I);
        st_dev(&W->a_f[tid], spmv_row(n, W->idx_i + (size_t)tid * ELL_I, W->cnt_u, 1));
    } else {
        int r = tid - NI;
        if (r < NU) {
            int n = min(W->cnt_u[r], ELL_U);
            st_dev(&W->p_f[r], spmv_row(n, W->idx_u + (size_t)r * ELL_U, W->cnt_i, 1));
        }
    }
    gbar(W->bar, ep);

    // ---- P4: b = H a (user rows), q = H^T p (item rows) ----
    if (tid < NU) {
        int n = min(W->cnt_u[tid], ELL_U);
        st_dev(&W->b_f[tid], spmv_row(n, W->idx_u + (size_t)tid * ELL_U, W->a_f, 0));
    } else {
        int r = tid - NU;
        if (r < NI) {
            int n = min(W->cnt_i[r], ELL_I);
            st_dev(&W->q_f[r], spmv_row(n, W->idx_i + (size_t)r * ELL_I, W->p_f, 0));
        }
    }
    gbar(W->bar, ep);

    // ---- P5: degree vectors + fp32 working copies + layer-0 output cols ----
    if (tid < NU) {
        float r = (float)W->cnt_u[tid];
        float bf_ = W->b_f[tid];
        st_dev(&W->dv_u[tid], 1.0f / sqrtf(r + bf_ + EPSF));
        st_dev(&W->de1sq_i[tid], 1.0f / (r + EPSF));
        st_dev(&W->de2sq_i[tid], 1.0f / (bf_ + EPSF));
    }
    if (tid < NI) {
        float cdeg = (float)W->cnt_i[tid];
        float qf_ = W->q_f[tid];
        st_dev(&W->dv_i[tid], 1.0f / sqrtf(cdeg + qf_ + EPSF));
        st_dev(&W->de1sq_u[tid], 1.0f / (cdeg + EPSF));
        st_dev(&W->de2sq_u[tid], 1.0f / (qf_ + EPSF));
    }
    for (int t = tid; t < (NU + NI) * DE; t += TOTTHR) {
        if (t < NU * DE) {
            int i = t >> 6, l = t & 63;
            float v = isbf ? b2f(((const __hip_bfloat16*)A.ue)[t]) : ((const float*)A.ue)[t];
            st_dev(&W->Xu[0][t], v);
            float dv = 1.0f / sqrtf((float)W->cnt_u[i] + W->b_f[i] + EPSF);
            st_dev(&W->Xsu[0][t], f2bf(dv * v));
            size_t o = (size_t)i * 192 + l;
            if (isbf) ((__hip_bfloat16*)A.outp)[o] = __float2bfloat16(v);
            else ((float*)A.outp)[o] = v;
        } else {
            int s = t - NU * DE;
            int i = s >> 6, l = s & 63;
            float v = isbf ? b2f(((const __hip_bfloat16*)A.ie)[s]) : ((const float*)A.ie)[s];
            st_dev(&W->Xi[0][s], v);
            float dv = 1.0f / sqrtf((float)W->cnt_i[i] + W->q_f[i] + EPSF);
            st_dev(&W->Xsi[0][s], f2bf(dv * v));
            size_t o = (size_t)(NU + i) * 192 + l;
            if (isbf) ((__hip_bfloat16*)A.outp)[o] = __float2bfloat16(v);
            else ((float*)A.outp)[o] = v;
        }
    }
    gbar(W->bar, ep);

    // ---- P6..: the 12 SpMM phases (6 per layer, both channels; all SSA) ----
    for (int layer = 0; layer < 2; ++layer) {
        const void* w = layer ? A.w1 : A.w0;
        const void* bb = layer ? A.b1 : A.b0;
        int coloff = 64 + 64 * layer;

        // s1: T1 = A^T Xs
        spmm_phase(mkjob(W->cnt_i, W->idx_i, ELL_I, NI, W->Xsu[layer], W->T1u[layer],
                         0, 0, 0, 0, 0, 0, 0, 0),
                   mkjob(W->cnt_u, W->idx_u, ELL_U, NU, W->Xsi[layer], W->T1i[layer],
                         0, 0, 0, 0, 0, 0, 0, 0),
                   0, w, bb, A.outp, isbf, gwave, lane);
        gbar(W->bar, ep);
        // s2: T2 = A T1
        spmm_phase(mkjob(W->cnt_u, W->idx_u, ELL_U, NU, W->T1u[layer], W->T2u[layer],
                         0, 0, 0, 0, 0, 0, 0, 0),
                   mkjob(W->cnt_i, W->idx_i, ELL_I, NI, W->T1i[layer], W->T2i[layer],
                         0, 0, 0, 0, 0, 0, 0, 0),
                   0, w, bb, A.outp, isbf, gwave, lane);
        gbar(W->bar, ep);
        // s3: T3 = de2sq o (A^T T2)
        spmm_phase(mkjob(W->cnt_i, W->idx_i, ELL_I, NI, W->T2u[layer], W->T3u[layer],
                         W->de2sq_u, 0, 0, 0, 0, 0, 0, 0),
                   mkjob(W->cnt_u, W->idx_u, ELL_U, NU, W->T2i[layer], W->T3i[layer],
                         W->de2sq_i, 0, 0, 0, 0, 0, 0, 0),
                   1, w, bb, A.outp, isbf, gwave, lane);
        gbar(W->bar, ep);
        // s4: T4 = A T3
        spmm_phase(mkjob(W->cnt_u, W->idx_u, ELL_U, NU, W->T3u[layer], W->T4u[layer],
                         0, 0, 0, 0, 0, 0, 0, 0),
                   mkjob(W->cnt_i, W->idx_i, ELL_I, NI, W->T3i[layer], W->T4i[layer],
                         0, 0, 0, 0, 0, 0, 0, 0),
                   0, w, bb, A.outp, isbf, gwave, lane);
        gbar(W->bar, ep);
        // s5: S = A^T T4 + de1sq o T1
        spmm_phase(mkjob(W->cnt_i, W->idx_i, ELL_I, NI, W->T4u[layer], W->Su[layer],
                         W->de1sq_u, W->T1u[layer], 0, 0, 0, 0, 0, 0),
                   mkjob(W->cnt_u, W->idx_u, ELL_U, NU, W->T4i[layer], W->Si[layer],
                         W->de1sq_i, W->T1i[layer], 0, 0, 0, 0, 0, 0),
                   2, w, bb, A.outp, isbf, gwave, lane);
        gbar(W->bar, ep);
        // s6: M = dv o (A S) + X ; Xnext = M w + b ; Xs' = dv o Xnext ; emit out
        spmm_phase(mkjob(W->cnt_u, W->idx_u, ELL_U, NU, W->Su[layer], 0, 0, 0,
                         W->Xu[layer], W->dv_u, W->Xu[layer + 1], W->Xsu[layer + 1],
                         0, coloff),
                   mkjob(W->cnt_i, W->idx_i, ELL_I, NI, W->Si[layer], 0, 0, 0,
                         W->Xi[layer], W->dv_i, W->Xi[layer + 1], W->Xsi[layer + 1],
                         (size_t)NU * 192, coloff),
                   3, w, bb, A.outp, isbf, gwave, lane);
        if (layer == 0) gbar(W->bar, ep);  // Xu[1]/Xsu[1] feed next layer
    }
}

// ---------------- host ----------------

extern "C" void kernel_launch(void* const* d_in, const int* in_sizes, int n_in,
                              void* d_out, int out_size, void* d_ws, size_t ws_size,
                              hipStream_t stream) {
    FArgs A;
    A.Hp = d_in[0];
    A.ue = d_in[1];
    A.ie = d_in[2];
    A.w0 = d_in[3];
    A.b0 = d_in[4];
    A.w1 = d_in[5];
    A.b1 = d_in[6];
    A.W = (WS*)d_ws;
    A.outp = d_out;
    (void)ws_size; (void)n_in; (void)in_sizes; (void)out_size;

    init_k<<<(NU + NI) / 256, 256, 0, stream>>>(A.W);
    detect_dtype<<<131072 / 256, 256, 0, stream>>>((const u32*)A.Hp, A.W);
    fused<<<NBLK, NTHR, 0, stream>>>(A);
}